// Round 4
// baseline (54.471 us; speedup 1.0000x reference)
//
#include <hip/hip_runtime.h>
#include <math.h>

// TripletLoss: B=16384 rows, D=1024 fp32.
// dp=||a-p||, dn=||a-n||, loss=softplus(dp-dn), out = mean(loss).
// Memory-bound: 192 MiB read once -> ~32us floor at 6.3 TB/s.
//
// R4: single kernel. Epilogue lessons:
//   R2: 2048x __threadfence (L2 writeback) serialized -> +68us. NEVER.
//   R3: 2048x atomicAdd to ONE address -> RMW convoy -> +17us.
//   R4: 32 spread slots (256B apart, parallel TCC lines) + fence-free
//       last-block finish via vmcnt(0) + ticket counter. Atomics are
//       memory-side coherent across XCDs; no cache maintenance needed.

#define B_ROWS 16384
#define D_DIM  1024
#define NBLOCKS 2048      // 4 waves/block -> 8192 waves, 2 rows per wave
#define NSLOTS 32
#define SLOT_STRIDE 64    // floats: 256B between slots -> distinct lines/channels

__global__ __launch_bounds__(256) void triplet_slots_kernel(
    const float* __restrict__ a,
    const float* __restrict__ p,
    const float* __restrict__ n,
    float* __restrict__ slots,          // NSLOTS spread accumulators (zeroed)
    unsigned int* __restrict__ counter, // ticket (zeroed)
    float* __restrict__ out)
{
    const int wave = threadIdx.x >> 6;   // 0..3
    const int lane = threadIdx.x & 63;
    const int globalWave = blockIdx.x * 4 + wave;
    const int totalWaves = gridDim.x * 4;

    float acc = 0.0f;  // per-wave loss accumulator (lane 0 only meaningful)

    for (int row = globalWave; row < B_ROWS; row += totalWaves) {
        const float4* a4 = (const float4*)(a + (size_t)row * D_DIM);
        const float4* p4 = (const float4*)(p + (size_t)row * D_DIM);
        const float4* n4 = (const float4*)(n + (size_t)row * D_DIM);
        float sp = 0.0f, sn = 0.0f;
        #pragma unroll
        for (int k = 0; k < 4; ++k) {
            const int idx = lane + 64 * k;   // coalesced: 64 lanes x 16B contiguous
            float4 av = a4[idx];
            float4 pv = p4[idx];
            float4 nv = n4[idx];
            float d0 = av.x - pv.x, d1 = av.y - pv.y,
                  d2 = av.z - pv.z, d3 = av.w - pv.w;
            sp += d0*d0 + d1*d1 + d2*d2 + d3*d3;
            d0 = av.x - nv.x; d1 = av.y - nv.y;
            d2 = av.z - nv.z; d3 = av.w - nv.w;
            sn += d0*d0 + d1*d1 + d2*d2 + d3*d3;
        }
        // 64-lane butterfly reduce (wave = 64 on CDNA)
        #pragma unroll
        for (int off = 32; off > 0; off >>= 1) {
            sp += __shfl_xor(sp, off, 64);
            sn += __shfl_xor(sn, off, 64);
        }
        if (lane == 0) {
            float dp = sqrtf(sp);
            float dn = sqrtf(sn);
            float x  = dp - dn;
            // stable softplus: logaddexp(0,x) = max(x,0) + log1p(exp(-|x|))
            acc += fmaxf(x, 0.0f) + log1pf(expf(-fabsf(x)));
        }
    }

    __shared__ float smem[4];
    if (lane == 0) smem[wave] = acc;
    __syncthreads();

    __shared__ unsigned int s_ticket;
    if (threadIdx.x == 0) {
        float block_sum = smem[0] + smem[1] + smem[2] + smem[3];
        // Payload: spread across 32 distinct lines -> no RMW convoy.
        float old = atomicAdd(&slots[(blockIdx.x & (NSLOTS - 1)) * SLOT_STRIDE],
                              block_sum);
        asm volatile("" :: "v"(old));              // keep returned value live
        asm volatile("s_waitcnt vmcnt(0)" ::: "memory");  // RMW done at coherence pt
        s_ticket = atomicAdd(counter, 1u);         // completion ticket (relaxed)
    }
    __syncthreads();

    if (s_ticket == (unsigned)(NBLOCKS - 1)) {
        // Last finisher: every other block's slot-add completed (vmcnt-acked)
        // before its ticket increment. Read slots coherently via RMW+0.
        float v = 0.0f;
        if (threadIdx.x < NSLOTS)
            v = atomicAdd(&slots[threadIdx.x * SLOT_STRIDE], 0.0f);
        #pragma unroll
        for (int off = 32; off > 0; off >>= 1)
            v += __shfl_xor(v, off, 64);
        if (threadIdx.x == 0)
            out[0] = v * (1.0f / (float)B_ROWS);
    }
}

extern "C" void kernel_launch(void* const* d_in, const int* in_sizes, int n_in,
                              void* d_out, int out_size, void* d_ws, size_t ws_size,
                              hipStream_t stream) {
    const float* anchor   = (const float*)d_in[0];
    const float* positive = (const float*)d_in[1];
    const float* negative = (const float*)d_in[2];
    float* out = (float*)d_out;
    float* slots = (float*)d_ws;                               // 32 x 256B = 8192 B
    unsigned int* counter = (unsigned int*)((char*)d_ws + NSLOTS * SLOT_STRIDE * sizeof(float));

    // Slots + counter must be zero at kernel start every call (ws poisoned
    // 0xAA once, never re-poisoned). One contiguous async memset node.
    hipMemsetAsync(d_ws, 0, NSLOTS * SLOT_STRIDE * sizeof(float) + sizeof(unsigned int), stream);

    triplet_slots_kernel<<<NBLOCKS, 256, 0, stream>>>(anchor, positive, negative,
                                                      slots, counter, out);
}

// Round 5
// 42.238 us; speedup vs baseline: 1.2896x; 1.2896x over previous
//
#include <hip/hip_runtime.h>
#include <math.h>

// TripletLoss: B=16384 rows, D=1024 fp32.
// dp=||a-p||, dn=||a-n||, loss=softplus(dp-dn), out = mean(loss).
// Memory-bound: 192 MiB read once -> ~32us floor at 6.3 TB/s.
//
// Epilogue lessons (harness graph timing, main loop ~33us):
//   R1: two kernels                         -> 36.7us (+3.7 launch/dispatch)
//   R2: 2048x __threadfence                 -> 105us  (L2 writeback serializes)
//   R3: 2048x atomicAdd on ONE address      -> 54us   (~8ns x 2048 RMW convoy)
//   R4: payload spread BUT one ticket addr  -> 54us   (convoy just moved)
// R5: hierarchical — max 64 RMWs on any single address:
//   32 slot-lines (256B apart): {float sum, uint local_ticket} each, 64 blocks
//   per group. Group leader (local==63) hits one 32-way global ticket. Last
//   leader reduces the 32 sums. All ordering via atomic completion + vmcnt(0);
//   no __threadfence anywhere.

#define B_ROWS 16384
#define D_DIM  1024
#define NBLOCKS 2048      // 4 waves/block -> 8192 waves, 2 rows per wave
#define NSLOTS 32
#define SLOT_STRIDE 64    // floats: 256B between slot lines

__global__ __launch_bounds__(256) void triplet_hier_kernel(
    const float* __restrict__ a,
    const float* __restrict__ p,
    const float* __restrict__ n,
    float* __restrict__ slots,          // 32 lines: [0]=sum, [1]=local ticket
    unsigned int* __restrict__ gcnt,    // global ticket (leaders only)
    float* __restrict__ out)
{
    const int wave = threadIdx.x >> 6;   // 0..3
    const int lane = threadIdx.x & 63;
    const int globalWave = blockIdx.x * 4 + wave;
    const int totalWaves = gridDim.x * 4;

    float acc = 0.0f;  // per-wave loss accumulator (lane 0 only meaningful)

    for (int row = globalWave; row < B_ROWS; row += totalWaves) {
        const float4* a4 = (const float4*)(a + (size_t)row * D_DIM);
        const float4* p4 = (const float4*)(p + (size_t)row * D_DIM);
        const float4* n4 = (const float4*)(n + (size_t)row * D_DIM);
        float sp = 0.0f, sn = 0.0f;
        #pragma unroll
        for (int k = 0; k < 4; ++k) {
            const int idx = lane + 64 * k;   // coalesced: 64 lanes x 16B contiguous
            float4 av = a4[idx];
            float4 pv = p4[idx];
            float4 nv = n4[idx];
            float d0 = av.x - pv.x, d1 = av.y - pv.y,
                  d2 = av.z - pv.z, d3 = av.w - pv.w;
            sp += d0*d0 + d1*d1 + d2*d2 + d3*d3;
            d0 = av.x - nv.x; d1 = av.y - nv.y;
            d2 = av.z - nv.z; d3 = av.w - nv.w;
            sn += d0*d0 + d1*d1 + d2*d2 + d3*d3;
        }
        // 64-lane butterfly reduce (wave = 64 on CDNA)
        #pragma unroll
        for (int off = 32; off > 0; off >>= 1) {
            sp += __shfl_xor(sp, off, 64);
            sn += __shfl_xor(sn, off, 64);
        }
        if (lane == 0) {
            float dp = sqrtf(sp);
            float dn = sqrtf(sn);
            float x  = dp - dn;
            // stable softplus: logaddexp(0,x) = max(x,0) + log1p(exp(-|x|))
            acc += fmaxf(x, 0.0f) + log1pf(expf(-fabsf(x)));
        }
    }

    __shared__ float smem[4];
    if (lane == 0) smem[wave] = acc;
    __syncthreads();

    __shared__ int s_final;
    if (threadIdx.x == 0) {
        s_final = 0;
        float block_sum = smem[0] + smem[1] + smem[2] + smem[3];
        float* slot = slots + (blockIdx.x & (NSLOTS - 1)) * SLOT_STRIDE;

        // Payload: 64-way convoy per line, 32 lines in parallel.
        float old = atomicAdd(slot, block_sum);
        asm volatile("" :: "v"(old));                     // keep RMW result live
        asm volatile("s_waitcnt vmcnt(0)" ::: "memory");  // payload at coherence pt

        unsigned lt = atomicAdd((unsigned int*)(slot + 1), 1u);
        if (lt == 63u) {  // group leader: my group's 64 payloads are complete
            asm volatile("s_waitcnt vmcnt(0)" ::: "memory");
            unsigned gt = atomicAdd(gcnt, 1u);            // 32-way convoy
            if (gt == (unsigned)(NSLOTS - 1)) s_final = 1;
        }
    }
    __syncthreads();

    if (s_final) {
        // Last leader: all 2048 payloads complete. RMW-read the 32 sums
        // (coherence-point reads, no acquire fence needed).
        float v = 0.0f;
        if (threadIdx.x < NSLOTS)
            v = atomicAdd(&slots[threadIdx.x * SLOT_STRIDE], 0.0f);
        #pragma unroll
        for (int off = 32; off > 0; off >>= 1)
            v += __shfl_xor(v, off, 64);
        if (threadIdx.x == 0)
            out[0] = v * (1.0f / (float)B_ROWS);
    }
}

extern "C" void kernel_launch(void* const* d_in, const int* in_sizes, int n_in,
                              void* d_out, int out_size, void* d_ws, size_t ws_size,
                              hipStream_t stream) {
    const float* anchor   = (const float*)d_in[0];
    const float* positive = (const float*)d_in[1];
    const float* negative = (const float*)d_in[2];
    float* out = (float*)d_out;
    float* slots = (float*)d_ws;                               // 32 x 256B = 8192 B
    unsigned int* gcnt = (unsigned int*)((char*)d_ws + NSLOTS * SLOT_STRIDE * sizeof(float));

    // Slots (sum + local tickets) and global ticket must be zero each call
    // (ws poisoned 0xAA once, never re-poisoned). One async memset node.
    hipMemsetAsync(d_ws, 0,
                   NSLOTS * SLOT_STRIDE * sizeof(float) + sizeof(unsigned int),
                   stream);

    triplet_hier_kernel<<<NBLOCKS, 256, 0, stream>>>(anchor, positive, negative,
                                                     slots, gcnt, out);
}